// Round 1
// baseline (967.326 us; speedup 1.0000x reference)
//
#include <hip/hip_runtime.h>
#include <hip/hip_bf16.h>
#include <cstdint>

// Problem constants (B=4, S=2048, H=2048, I=1024, E=8, K=2)
#define T_TOKENS 8192
#define H_DIM 2048
#define I_DIM 1024
#define N_EXPERTS 8
#define PAIRS (T_TOKENS * 2)
#define MAX_TILES 136          // sum_e ceil(n_e/128) <= 16384/128 + 8
#define MAX_ROWS (MAX_TILES * 128)

using f32x4 = __attribute__((ext_vector_type(4))) float;
using bfv   = __attribute__((ext_vector_type(8))) short;          // MFMA a/b frag (8 bf16)
using u16x4 = __attribute__((ext_vector_type(4))) unsigned short;
using u16x8 = __attribute__((ext_vector_type(8))) unsigned short;

__device__ inline unsigned short f2bf(float f) {
  unsigned int u = __float_as_uint(f);
  u += 0x7FFFu + ((u >> 16) & 1u);          // RTN-even
  return (unsigned short)(u >> 16);
}
__device__ inline float bf2f(unsigned short u) {
  return __uint_as_float((unsigned int)u << 16);
}

// ---------------- Router: RMSNorm folded into logits, softmax, top-2 (fp32) ----------------
__global__ __launch_bounds__(256) void moe_router_kernel(
    const float* __restrict__ X, const float* __restrict__ norm_w,
    const float* __restrict__ rw, float* __restrict__ probs,
    float* __restrict__ topw, int* __restrict__ topi,
    unsigned int* __restrict__ counts) {
  int t = blockIdx.x;
  int tid = threadIdx.x;
  const float* x = X + (size_t)t * H_DIM;
  float ss = 0.f;
  float dot[8] = {0.f, 0.f, 0.f, 0.f, 0.f, 0.f, 0.f, 0.f};
  for (int i = tid; i < H_DIM; i += 256) {
    float v = x[i];
    float nv = v * norm_w[i];
    ss += v * v;
#pragma unroll
    for (int e = 0; e < 8; ++e) dot[e] += nv * rw[e * H_DIM + i];
  }
  __shared__ float red[9 * 256];
  red[tid] = ss;
#pragma unroll
  for (int e = 0; e < 8; ++e) red[(e + 1) * 256 + tid] = dot[e];
  __syncthreads();
  for (int s = 128; s > 0; s >>= 1) {
    if (tid < s) {
#pragma unroll
      for (int v = 0; v < 9; ++v) red[v * 256 + tid] += red[v * 256 + tid + s];
    }
    __syncthreads();
  }
  if (tid == 0) {
    float var = red[0] / (float)H_DIM;
    float rs = rsqrtf(var + 1e-6f);
    float lg[8], mx = -1e30f;
#pragma unroll
    for (int e = 0; e < 8; ++e) {
      lg[e] = red[(e + 1) * 256] * rs;
      mx = fmaxf(mx, lg[e]);
    }
    float pe[8], sum = 0.f;
#pragma unroll
    for (int e = 0; e < 8; ++e) { pe[e] = expf(lg[e] - mx); sum += pe[e]; }
    float inv = 1.f / sum;
#pragma unroll
    for (int e = 0; e < 8; ++e) { pe[e] *= inv; probs[t * 8 + e] = pe[e]; }
    // top-2, lowest index wins ties (matches jax.lax.top_k)
    int b1 = 0; float p1 = pe[0];
#pragma unroll
    for (int e = 1; e < 8; ++e) if (pe[e] > p1) { p1 = pe[e]; b1 = e; }
    int b2 = -1; float p2 = -1.f;
#pragma unroll
    for (int e = 0; e < 8; ++e) if (e != b1 && pe[e] > p2) { p2 = pe[e]; b2 = e; }
    float wsum = p1 + p2;
    topw[t * 2] = p1 / wsum;
    topw[t * 2 + 1] = p2 / wsum;
    topi[t * 2] = b1;
    topi[t * 2 + 1] = b2;
    atomicAdd(&counts[b1], 1u);
    atomicAdd(&counts[b2], 1u);
  }
}

// ---------------- importance[e] = sum_t probs[t,e] ----------------
__global__ __launch_bounds__(256) void moe_importance_kernel(
    const float* __restrict__ probs, float* __restrict__ impSum) {
  int e = blockIdx.x, tid = threadIdx.x;
  float s = 0.f;
  for (int t = tid; t < T_TOKENS; t += 256) s += probs[t * 8 + e];
  __shared__ float red[256];
  red[tid] = s;
  __syncthreads();
  for (int st = 128; st > 0; st >>= 1) {
    if (tid < st) red[tid] += red[tid + st];
    __syncthreads();
  }
  if (tid == 0) impSum[e] = red[0];
}

// ---------------- tile offsets (prefix over ceil(n_e/128)) + aux loss ----------------
__global__ void moe_offsets_aux_kernel(const unsigned int* __restrict__ counts,
                                       const float* __restrict__ impSum,
                                       int* __restrict__ tileOff,
                                       float* __restrict__ out_aux) {
  if (threadIdx.x == 0 && blockIdx.x == 0) {
    int acc = 0;
    for (int e = 0; e < 8; ++e) {
      tileOff[e] = acc;
      acc += (int)((counts[e] + 127u) >> 7);
    }
    tileOff[8] = acc;
    float a = 0.f;
    for (int e = 0; e < 8; ++e)
      a += (impSum[e] / (float)T_TOKENS) * ((float)counts[e] / (float)PAIRS);
    out_aux[0] = a * (float)N_EXPERTS;
  }
}

// ---------------- bucket pairs into padded per-expert row space ----------------
__global__ __launch_bounds__(256) void moe_assign_kernel(
    const int* __restrict__ topi, const int* __restrict__ tileOff,
    unsigned int* __restrict__ cursors, int* __restrict__ row2pair) {
  int p = blockIdx.x * 256 + threadIdx.x;
  if (p >= PAIRS) return;
  int e = topi[p];
  unsigned int pos = atomicAdd(&cursors[e], 1u);
  row2pair[tileOff[e] * 128 + (int)pos] = p;
}

// ---------------- Stage A: P = silu(X@gate^T) * (X@up^T), bf16 MFMA, fused ----------------
// tile 128x128, BK=64, 4 waves (2x2 quadrants), two accumulators (gate, up)
__global__ __launch_bounds__(256) void moe_stage_a_kernel(
    const float* __restrict__ X, const float* __restrict__ gate_w,
    const float* __restrict__ up_w, const int* __restrict__ row2pair,
    const int* __restrict__ tileOff, unsigned short* __restrict__ P) {
  __shared__ int sTok[128];
  __shared__ unsigned short sA[128 * 72];   // 64 + 8 pad (keeps 16B align, balanced banks)
  __shared__ unsigned short sBg[128 * 72];
  __shared__ unsigned short sBu[128 * 72];
  int mt = blockIdx.x, nt = blockIdx.y;
  if (mt >= tileOff[8]) return;
  int e = 0;
#pragma unroll
  for (int k = 1; k < 8; ++k) if (tileOff[k] <= mt) e = k;
  int row0 = mt * 128;
  int n0 = nt * 128;
  int tid = threadIdx.x;
  if (tid < 128) {
    int pr = row2pair[row0 + tid];
    sTok[tid] = (pr >= 0) ? (pr >> 1) : 0;
  }
  __syncthreads();
  int lane = tid & 63, wid = tid >> 6;
  int wm = wid >> 1, wn = wid & 1;
  int lrow = lane & 15;
  int lko = (lane >> 4) << 3;
  f32x4 accG[4][4] = {};
  f32x4 accU[4][4] = {};
  const float* gw = gate_w + (size_t)e * (size_t)(I_DIM * H_DIM);
  const float* uw = up_w + (size_t)e * (size_t)(I_DIM * H_DIM);

  for (int kk = 0; kk < H_DIM; kk += 64) {
    // stage A tile: 128 rows x 64 k, fp32 -> bf16 (gathered rows)
#pragma unroll
    for (int it = 0; it < 8; ++it) {
      int u = tid + it * 256;
      int r = u >> 4, c4 = u & 15;
      f32x4 v = *reinterpret_cast<const f32x4*>(X + (size_t)sTok[r] * H_DIM + kk + c4 * 4);
      u16x4 b = {f2bf(v[0]), f2bf(v[1]), f2bf(v[2]), f2bf(v[3])};
      *reinterpret_cast<u16x4*>(&sA[r * 72 + c4 * 4]) = b;
    }
    // stage Bg tile: gate_w[e][n0+r][kk..]
#pragma unroll
    for (int it = 0; it < 8; ++it) {
      int u = tid + it * 256;
      int r = u >> 4, c4 = u & 15;
      f32x4 v = *reinterpret_cast<const f32x4*>(gw + (size_t)(n0 + r) * H_DIM + kk + c4 * 4);
      u16x4 b = {f2bf(v[0]), f2bf(v[1]), f2bf(v[2]), f2bf(v[3])};
      *reinterpret_cast<u16x4*>(&sBg[r * 72 + c4 * 4]) = b;
    }
    // stage Bu tile
#pragma unroll
    for (int it = 0; it < 8; ++it) {
      int u = tid + it * 256;
      int r = u >> 4, c4 = u & 15;
      f32x4 v = *reinterpret_cast<const f32x4*>(uw + (size_t)(n0 + r) * H_DIM + kk + c4 * 4);
      u16x4 b = {f2bf(v[0]), f2bf(v[1]), f2bf(v[2]), f2bf(v[3])};
      *reinterpret_cast<u16x4*>(&sBu[r * 72 + c4 * 4]) = b;
    }
    __syncthreads();
#pragma unroll
    for (int ks = 0; ks < 2; ++ks) {
      int co = ks * 32 + lko;
      bfv a[4], bg[4], bu[4];
#pragma unroll
      for (int m = 0; m < 4; ++m)
        a[m] = *reinterpret_cast<const bfv*>(&sA[(wm * 64 + m * 16 + lrow) * 72 + co]);
#pragma unroll
      for (int n = 0; n < 4; ++n) {
        bg[n] = *reinterpret_cast<const bfv*>(&sBg[(wn * 64 + n * 16 + lrow) * 72 + co]);
        bu[n] = *reinterpret_cast<const bfv*>(&sBu[(wn * 64 + n * 16 + lrow) * 72 + co]);
      }
#pragma unroll
      for (int m = 0; m < 4; ++m) {
#pragma unroll
        for (int n = 0; n < 4; ++n) {
          accG[m][n] = __builtin_amdgcn_mfma_f32_16x16x32_bf16(a[m], bg[n], accG[m][n], 0, 0, 0);
          accU[m][n] = __builtin_amdgcn_mfma_f32_16x16x32_bf16(a[m], bu[n], accU[m][n], 0, 0, 0);
        }
      }
    }
    __syncthreads();
  }
  // epilogue: P = silu(g) * u   (C/D layout: row=(lane>>4)*4+j, col=lane&15)
  int rbase = (lane >> 4) << 2;
#pragma unroll
  for (int m = 0; m < 4; ++m) {
#pragma unroll
    for (int n = 0; n < 4; ++n) {
#pragma unroll
      for (int j = 0; j < 4; ++j) {
        float g = accG[m][n][j];
        float uu = accU[m][n][j];
        float pv = (g / (1.f + expf(-g))) * uu;
        int rl = wm * 64 + m * 16 + rbase + j;
        int cl = wn * 64 + n * 16 + lrow;
        P[(size_t)(row0 + rl) * I_DIM + n0 + cl] = f2bf(pv);
      }
    }
  }
}

// ---------------- Stage B: O = P @ down^T, scatter rows to per-pair slots ----------------
__global__ __launch_bounds__(256) void moe_stage_b_kernel(
    const unsigned short* __restrict__ P, const float* __restrict__ down_w,
    const int* __restrict__ row2pair, const int* __restrict__ tileOff,
    unsigned short* __restrict__ Opairs) {
  __shared__ int sPair[128];
  __shared__ unsigned short sA[128 * 72];
  __shared__ unsigned short sB[128 * 72];
  int mt = blockIdx.x, nt = blockIdx.y;
  if (mt >= tileOff[8]) return;
  int e = 0;
#pragma unroll
  for (int k = 1; k < 8; ++k) if (tileOff[k] <= mt) e = k;
  int row0 = mt * 128;
  int h0 = nt * 128;
  int tid = threadIdx.x;
  if (tid < 128) sPair[tid] = row2pair[row0 + tid];
  __syncthreads();
  int lane = tid & 63, wid = tid >> 6;
  int wm = wid >> 1, wn = wid & 1;
  int lrow = lane & 15;
  int lko = (lane >> 4) << 3;
  f32x4 acc[4][4] = {};
  const float* dw = down_w + (size_t)e * (size_t)(H_DIM * I_DIM);

  for (int kk = 0; kk < I_DIM; kk += 64) {
    // A: bf16 copy of P tile (1024 x u16x8)
#pragma unroll
    for (int it = 0; it < 4; ++it) {
      int u = tid + it * 256;
      int r = u >> 3, c8 = u & 7;
      u16x8 v = *reinterpret_cast<const u16x8*>(P + (size_t)(row0 + r) * I_DIM + kk + c8 * 8);
      *reinterpret_cast<u16x8*>(&sA[r * 72 + c8 * 8]) = v;
    }
    // B: down_w[e][h0+r][kk..], fp32 -> bf16
#pragma unroll
    for (int it = 0; it < 8; ++it) {
      int u = tid + it * 256;
      int r = u >> 4, c4 = u & 15;
      f32x4 v = *reinterpret_cast<const f32x4*>(dw + (size_t)(h0 + r) * I_DIM + kk + c4 * 4);
      u16x4 b = {f2bf(v[0]), f2bf(v[1]), f2bf(v[2]), f2bf(v[3])};
      *reinterpret_cast<u16x4*>(&sB[r * 72 + c4 * 4]) = b;
    }
    __syncthreads();
#pragma unroll
    for (int ks = 0; ks < 2; ++ks) {
      int co = ks * 32 + lko;
      bfv a[4], b[4];
#pragma unroll
      for (int m = 0; m < 4; ++m)
        a[m] = *reinterpret_cast<const bfv*>(&sA[(wm * 64 + m * 16 + lrow) * 72 + co]);
#pragma unroll
      for (int n = 0; n < 4; ++n)
        b[n] = *reinterpret_cast<const bfv*>(&sB[(wn * 64 + n * 16 + lrow) * 72 + co]);
#pragma unroll
      for (int m = 0; m < 4; ++m) {
#pragma unroll
        for (int n = 0; n < 4; ++n)
          acc[m][n] = __builtin_amdgcn_mfma_f32_16x16x32_bf16(a[m], b[n], acc[m][n], 0, 0, 0);
      }
    }
    __syncthreads();
  }
  int rbase = (lane >> 4) << 2;
#pragma unroll
  for (int m = 0; m < 4; ++m) {
#pragma unroll
    for (int n = 0; n < 4; ++n) {
#pragma unroll
      for (int j = 0; j < 4; ++j) {
        int rl = wm * 64 + m * 16 + rbase + j;
        int pr = sPair[rl];
        if (pr >= 0) {
          int cl = wn * 64 + n * 16 + lrow;
          Opairs[(size_t)pr * H_DIM + h0 + cl] = f2bf(acc[m][n][j]);
        }
      }
    }
  }
}

// ---------------- Combine: out[t] = 4 * (w0*O[2t] + w1*O[2t+1]) ----------------
__global__ __launch_bounds__(256) void moe_combine_kernel(
    const unsigned short* __restrict__ Opairs, const float* __restrict__ topw,
    float* __restrict__ out) {
  size_t g = (size_t)blockIdx.x * 256 + threadIdx.x;
  size_t base = g * 8;
  int t = (int)(base >> 11);
  int h = (int)(base & 2047);
  float w0 = topw[t * 2] * 4.f;
  float w1 = topw[t * 2 + 1] * 4.f;
  u16x8 o0 = *reinterpret_cast<const u16x8*>(Opairs + (size_t)(t * 2) * H_DIM + h);
  u16x8 o1 = *reinterpret_cast<const u16x8*>(Opairs + (size_t)(t * 2 + 1) * H_DIM + h);
  f32x4 r0, r1;
#pragma unroll
  for (int j = 0; j < 4; ++j) r0[j] = w0 * bf2f(o0[j]) + w1 * bf2f(o1[j]);
#pragma unroll
  for (int j = 0; j < 4; ++j) r1[j] = w0 * bf2f(o0[4 + j]) + w1 * bf2f(o1[4 + j]);
  *reinterpret_cast<f32x4*>(out + base) = r0;
  *reinterpret_cast<f32x4*>(out + base + 4) = r1;
}

// ---------------- launch ----------------
// ws layout (bytes), total ~103.3 MB:
//   P        @ 0          : 17408*1024*2 = 35,651,584
//   Opairs   @ 35,651,584 : 16384*2048*2 = 67,108,864
//   probs    @ 102,760,448: 8192*8*4     =    262,144
//   topw     @ 103,022,592: 16384*4      =     65,536
//   topi     @ 103,088,128: 16384*4      =     65,536
//   row2pair @ 103,153,664: 17408*4      =     69,632
//   ctrl     @ 103,223,296: 256          (counts, cursors, impSum, tileOff)
extern "C" void kernel_launch(void* const* d_in, const int* in_sizes, int n_in,
                              void* d_out, int out_size, void* d_ws, size_t ws_size,
                              hipStream_t stream) {
  const float* X = (const float*)d_in[0];
  const float* norm_w = (const float*)d_in[1];
  const float* router_w = (const float*)d_in[2];
  const float* gate_w = (const float*)d_in[3];
  const float* up_w = (const float*)d_in[4];
  const float* down_w = (const float*)d_in[5];
  float* out = (float*)d_out;

  char* ws = (char*)d_ws;
  unsigned short* P = (unsigned short*)(ws);
  unsigned short* Opairs = (unsigned short*)(ws + 35651584);
  float* probs = (float*)(ws + 102760448);
  float* topw = (float*)(ws + 103022592);
  int* topi = (int*)(ws + 103088128);
  int* row2pair = (int*)(ws + 103153664);
  char* ctrl = ws + 103223296;
  unsigned int* counts = (unsigned int*)(ctrl);
  unsigned int* cursors = (unsigned int*)(ctrl + 32);
  float* impSum = (float*)(ctrl + 64);
  int* tileOff = (int*)(ctrl + 96);

  hipMemsetAsync(ctrl, 0, 256, stream);
  hipMemsetAsync(row2pair, 0xFF, (size_t)MAX_ROWS * 4, stream);

  moe_router_kernel<<<T_TOKENS, 256, 0, stream>>>(X, norm_w, router_w, probs, topw, topi, counts);
  moe_importance_kernel<<<N_EXPERTS, 256, 0, stream>>>(probs, impSum);
  moe_offsets_aux_kernel<<<1, 64, 0, stream>>>(counts, impSum, tileOff, out + 16777216);
  moe_assign_kernel<<<PAIRS / 256, 256, 0, stream>>>(topi, tileOff, cursors, row2pair);
  moe_stage_a_kernel<<<dim3(MAX_TILES, I_DIM / 128), 256, 0, stream>>>(
      X, gate_w, up_w, row2pair, tileOff, P);
  moe_stage_b_kernel<<<dim3(MAX_TILES, H_DIM / 128), 256, 0, stream>>>(
      P, down_w, row2pair, tileOff, Opairs);
  moe_combine_kernel<<<T_TOKENS, 256, 0, stream>>>(Opairs, topw, out);
}

// Round 2
// 765.894 us; speedup vs baseline: 1.2630x; 1.2630x over previous
//
#include <hip/hip_runtime.h>
#include <hip/hip_bf16.h>
#include <cstdint>

// Problem constants (B=4, S=2048, H=2048, I=1024, E=8, K=2)
#define T_TOKENS 8192
#define H_DIM 2048
#define I_DIM 1024
#define N_EXPERTS 8
#define PAIRS (T_TOKENS * 2)
#define PHASE_TILES 72            // 8192/128 + 8 buckets worst-case padding
#define TOT_TILES (PHASE_TILES*2) // 144
#define TOT_ROWS (TOT_TILES * 128)

using f32x4 = __attribute__((ext_vector_type(4))) float;
using bfv   = __attribute__((ext_vector_type(8))) short;          // MFMA a/b frag (8 bf16)
using u16x8 = __attribute__((ext_vector_type(8))) unsigned short;

typedef __attribute__((address_space(3))) unsigned int lds_u32;
typedef __attribute__((address_space(1))) unsigned int glb_u32;

// async global->LDS, 16B per lane; LDS dest = wave-uniform base + lane*16
__device__ __forceinline__ void gll16(const void* g, void* l) {
  __builtin_amdgcn_global_load_lds((const glb_u32*)g, (lds_u32*)l, 16, 0, 0);
}

__device__ inline unsigned short f2bf(float f) {
  unsigned int u = __float_as_uint(f);
  u += 0x7FFFu + ((u >> 16) & 1u);          // RTN-even
  return (unsigned short)(u >> 16);
}
__device__ inline float bf2f(unsigned short u) {
  return __uint_as_float((unsigned int)u << 16);
}

// ---------------- fp32 -> bf16 bulk convert ----------------
__global__ __launch_bounds__(256) void moe_convert_kernel(
    const float* __restrict__ src, unsigned short* __restrict__ dst, int n8) {
  int i = blockIdx.x * 256 + threadIdx.x;
  if (i >= n8) return;
  size_t o = (size_t)i * 8;
  f32x4 a = *reinterpret_cast<const f32x4*>(src + o);
  f32x4 b = *reinterpret_cast<const f32x4*>(src + o + 4);
  u16x8 r = {f2bf(a[0]), f2bf(a[1]), f2bf(a[2]), f2bf(a[3]),
             f2bf(b[0]), f2bf(b[1]), f2bf(b[2]), f2bf(b[3])};
  *reinterpret_cast<u16x8*>(dst + o) = r;
}

// ---------------- Router: RMSNorm folded into logits, softmax, top-2 (fp32) ----------------
// Also emits bf16 copy of X (free: we read X anyway).
__global__ __launch_bounds__(256) void moe_router_kernel(
    const float* __restrict__ X, const float* __restrict__ norm_w,
    const float* __restrict__ rw, float* __restrict__ probs,
    float* __restrict__ topw, int* __restrict__ topi,
    unsigned int* __restrict__ counts, unsigned short* __restrict__ Xb, int writeXb) {
  int t = blockIdx.x;
  int tid = threadIdx.x;
  const float* x = X + (size_t)t * H_DIM;
  int base = tid * 8;                      // 256 threads x 8 = 2048 = H
  f32x4 v0 = *reinterpret_cast<const f32x4*>(x + base);
  f32x4 v1 = *reinterpret_cast<const f32x4*>(x + base + 4);
  if (writeXb) {
    u16x8 bx = {f2bf(v0[0]), f2bf(v0[1]), f2bf(v0[2]), f2bf(v0[3]),
                f2bf(v1[0]), f2bf(v1[1]), f2bf(v1[2]), f2bf(v1[3])};
    *reinterpret_cast<u16x8*>(Xb + (size_t)t * H_DIM + base) = bx;
  }
  f32x4 nw0 = *reinterpret_cast<const f32x4*>(norm_w + base);
  f32x4 nw1 = *reinterpret_cast<const f32x4*>(norm_w + base + 4);
  float vals[9];
  vals[0] = v0[0]*v0[0] + v0[1]*v0[1] + v0[2]*v0[2] + v0[3]*v0[3]
          + v1[0]*v1[0] + v1[1]*v1[1] + v1[2]*v1[2] + v1[3]*v1[3];
  f32x4 a0 = v0 * nw0, a1 = v1 * nw1;
#pragma unroll
  for (int e = 0; e < 8; ++e) {
    const float* r = rw + e * H_DIM + base;
    f32x4 r0 = *reinterpret_cast<const f32x4*>(r);
    f32x4 r1 = *reinterpret_cast<const f32x4*>(r + 4);
    f32x4 d = a0 * r0 + a1 * r1;
    vals[e + 1] = d[0] + d[1] + d[2] + d[3];
  }
#pragma unroll
  for (int v = 0; v < 9; ++v) {
    float s = vals[v];
#pragma unroll
    for (int off = 32; off > 0; off >>= 1) s += __shfl_xor(s, off);
    vals[v] = s;
  }
  __shared__ float red[4][9];
  int lane = tid & 63, w = tid >> 6;
  if (lane == 0) {
#pragma unroll
    for (int v = 0; v < 9; ++v) red[w][v] = vals[v];
  }
  __syncthreads();
  if (tid == 0) {
    float tot[9];
#pragma unroll
    for (int v = 0; v < 9; ++v) tot[v] = red[0][v] + red[1][v] + red[2][v] + red[3][v];
    float rs = rsqrtf(tot[0] / (float)H_DIM + 1e-6f);
    float lg[8], mx = -1e30f;
#pragma unroll
    for (int e = 0; e < 8; ++e) { lg[e] = tot[e + 1] * rs; mx = fmaxf(mx, lg[e]); }
    float pe[8], sum = 0.f;
#pragma unroll
    for (int e = 0; e < 8; ++e) { pe[e] = expf(lg[e] - mx); sum += pe[e]; }
    float inv = 1.f / sum;
#pragma unroll
    for (int e = 0; e < 8; ++e) { pe[e] *= inv; probs[t * 8 + e] = pe[e]; }
    int b1 = 0; float p1 = pe[0];
#pragma unroll
    for (int e = 1; e < 8; ++e) if (pe[e] > p1) { p1 = pe[e]; b1 = e; }
    int b2 = -1; float p2 = -1.f;
#pragma unroll
    for (int e = 0; e < 8; ++e) if (e != b1 && pe[e] > p2) { p2 = pe[e]; b2 = e; }
    float wsum = p1 + p2;
    topw[t * 2] = p1 / wsum;
    topw[t * 2 + 1] = p2 / wsum;
    topi[t * 2] = b1;
    topi[t * 2 + 1] = b2;
    atomicAdd(&counts[b1], 1u);        // slot-0 bucket = expert
    atomicAdd(&counts[8 + b2], 1u);    // slot-1 bucket = 8 + expert
  }
}

// ---------------- importance[e] = sum_t probs[t,e] ----------------
__global__ __launch_bounds__(256) void moe_importance_kernel(
    const float* __restrict__ probs, float* __restrict__ impSum) {
  int e = blockIdx.x, tid = threadIdx.x;
  float s = 0.f;
  for (int t = tid; t < T_TOKENS; t += 256) s += probs[t * 8 + e];
  __shared__ float red[256];
  red[tid] = s;
  __syncthreads();
  for (int st = 128; st > 0; st >>= 1) {
    if (tid < st) red[tid] += red[tid + st];
    __syncthreads();
  }
  if (tid == 0) impSum[e] = red[0];
}

// ---------------- tile offsets (prefix over ceil(n_b/128), 16 buckets) + aux loss ----------------
__global__ void moe_offsets_aux_kernel(const unsigned int* __restrict__ counts,
                                       const float* __restrict__ impSum,
                                       int* __restrict__ tileOff,
                                       float* __restrict__ out_aux) {
  if (threadIdx.x == 0 && blockIdx.x == 0) {
    int acc = 0;
    for (int b = 0; b < 16; ++b) {
      tileOff[b] = acc;
      acc += (int)((counts[b] + 127u) >> 7);
    }
    tileOff[16] = acc;
    float a = 0.f;
    for (int e = 0; e < 8; ++e) {
      float load = (float)(counts[e] + counts[8 + e]) / (float)PAIRS;
      a += (impSum[e] / (float)T_TOKENS) * load;
    }
    out_aux[0] = a * (float)N_EXPERTS;
  }
}

// ---------------- bucket pairs (expert x slot) into padded row space ----------------
__global__ __launch_bounds__(256) void moe_assign_kernel(
    const int* __restrict__ topi, const int* __restrict__ tileOff,
    unsigned int* __restrict__ cursors, int* __restrict__ row2pair) {
  int p = blockIdx.x * 256 + threadIdx.x;
  if (p >= PAIRS) return;
  int b = topi[p] + 8 * (p & 1);
  unsigned int pos = atomicAdd(&cursors[b], 1u);
  row2pair[tileOff[b] * 128 + (int)pos] = p;
}

// ---------------- Stage A: P = silu(X@gate^T) * (X@up^T), bf16 MFMA ----------------
// 128x128 tile, BK=64, 4 waves 2x2. PRE=1: global_load_lds from bf16 with
// source-side XOR swizzle (chunk ^= row&7); PRE=0: reg-stage fp32->bf16.
template <int PRE>
__global__ __launch_bounds__(256) void moe_stage_a(
    const float* __restrict__ Xf, const unsigned short* __restrict__ Xb,
    const float* __restrict__ gwf, const float* __restrict__ uwf,
    const unsigned short* __restrict__ gwb, const unsigned short* __restrict__ uwb,
    const int* __restrict__ row2pair, const int* __restrict__ tileOff,
    unsigned short* __restrict__ P) {
  __shared__ int sTok[128];
  __shared__ __align__(16) unsigned short sA[128 * 64];
  __shared__ __align__(16) unsigned short sBg[128 * 64];
  __shared__ __align__(16) unsigned short sBu[128 * 64];
  int mt = blockIdx.x;
  if (mt >= tileOff[16]) return;
  int nt = blockIdx.y;
  int b = 0;
#pragma unroll
  for (int k = 1; k < 16; ++k) if (tileOff[k] <= mt) b = k;
  int e = b & 7;
  int row0 = mt * 128, n0 = nt * 128;
  int tid = threadIdx.x;
  if (tid < 128) {
    int pr = row2pair[row0 + tid];
    sTok[tid] = (pr >= 0) ? (pr >> 1) : 0;
  }
  __syncthreads();
  int lane = tid & 63, w = tid >> 6;
  int wm = w >> 1, wn = w & 1;
  int rloc = lane >> 3, cch = lane & 7, swz = cch ^ rloc;
  size_t wb = (size_t)e * ((size_t)I_DIM * H_DIM);

  const unsigned short* srcA[4]; const unsigned short* srcG[4]; const unsigned short* srcU[4];
  const float* fA[4]; const float* fG[4]; const float* fU[4];
#pragma unroll
  for (int i = 0; i < 4; ++i) {
    int s = 4 * w + i;
    int row = s * 8 + rloc;
    int tok = sTok[row];
    int wrow = n0 + row;
    if constexpr (PRE) {
      srcA[i] = Xb + (size_t)tok * H_DIM + swz * 8;
      srcG[i] = gwb + wb + (size_t)wrow * H_DIM + swz * 8;
      srcU[i] = uwb + wb + (size_t)wrow * H_DIM + swz * 8;
    } else {
      fA[i] = Xf + (size_t)tok * H_DIM + cch * 8;
      fG[i] = gwf + wb + (size_t)wrow * H_DIM + cch * 8;
      fU[i] = uwf + wb + (size_t)wrow * H_DIM + cch * 8;
    }
  }
  int wrswz = rloc * 64 + (swz << 3);   // LDS write offset within slice (reg path)
  f32x4 accG[4][4] = {};
  f32x4 accU[4][4] = {};
  int lrow = lane & 15, grp = lane >> 4, sw7 = lane & 7;

  for (int kk = 0; kk < H_DIM; kk += 64) {
    if constexpr (PRE) {
#pragma unroll
      for (int i = 0; i < 4; ++i) {
        int lo = (4 * w + i) * 512;
        gll16(srcA[i] + kk, (void*)&sA[lo]);
        gll16(srcG[i] + kk, (void*)&sBg[lo]);
        gll16(srcU[i] + kk, (void*)&sBu[lo]);
      }
      asm volatile("s_waitcnt vmcnt(0)" ::: "memory");
    } else {
#pragma unroll
      for (int i = 0; i < 4; ++i) {
        int o = (4 * w + i) * 512 + wrswz;
        f32x4 x0 = *reinterpret_cast<const f32x4*>(fA[i] + kk);
        f32x4 x1 = *reinterpret_cast<const f32x4*>(fA[i] + kk + 4);
        u16x8 r = {f2bf(x0[0]), f2bf(x0[1]), f2bf(x0[2]), f2bf(x0[3]),
                   f2bf(x1[0]), f2bf(x1[1]), f2bf(x1[2]), f2bf(x1[3])};
        *reinterpret_cast<u16x8*>(&sA[o]) = r;
        x0 = *reinterpret_cast<const f32x4*>(fG[i] + kk);
        x1 = *reinterpret_cast<const f32x4*>(fG[i] + kk + 4);
        u16x8 rg = {f2bf(x0[0]), f2bf(x0[1]), f2bf(x0[2]), f2bf(x0[3]),
                    f2bf(x1[0]), f2bf(x1[1]), f2bf(x1[2]), f2bf(x1[3])};
        *reinterpret_cast<u16x8*>(&sBg[o]) = rg;
        x0 = *reinterpret_cast<const f32x4*>(fU[i] + kk);
        x1 = *reinterpret_cast<const f32x4*>(fU[i] + kk + 4);
        u16x8 ru = {f2bf(x0[0]), f2bf(x0[1]), f2bf(x0[2]), f2bf(x0[3]),
                    f2bf(x1[0]), f2bf(x1[1]), f2bf(x1[2]), f2bf(x1[3])};
        *reinterpret_cast<u16x8*>(&sBu[o]) = ru;
      }
    }
    __syncthreads();
#pragma unroll
    for (int ks = 0; ks < 2; ++ks) {
      int cs = ((ks * 4 + grp) ^ sw7) << 3;
      bfv a[4], bg[4], bu[4];
#pragma unroll
      for (int m = 0; m < 4; ++m)
        a[m] = *reinterpret_cast<const bfv*>(&sA[(wm * 64 + m * 16 + lrow) * 64 + cs]);
#pragma unroll
      for (int n = 0; n < 4; ++n) {
        bg[n] = *reinterpret_cast<const bfv*>(&sBg[(wn * 64 + n * 16 + lrow) * 64 + cs]);
        bu[n] = *reinterpret_cast<const bfv*>(&sBu[(wn * 64 + n * 16 + lrow) * 64 + cs]);
      }
#pragma unroll
      for (int m = 0; m < 4; ++m) {
#pragma unroll
        for (int n = 0; n < 4; ++n) {
          accG[m][n] = __builtin_amdgcn_mfma_f32_16x16x32_bf16(a[m], bg[n], accG[m][n], 0, 0, 0);
          accU[m][n] = __builtin_amdgcn_mfma_f32_16x16x32_bf16(a[m], bu[n], accU[m][n], 0, 0, 0);
        }
      }
    }
    __syncthreads();
  }
  int rbase = grp << 2;
#pragma unroll
  for (int m = 0; m < 4; ++m) {
#pragma unroll
    for (int n = 0; n < 4; ++n) {
#pragma unroll
      for (int j = 0; j < 4; ++j) {
        float g = accG[m][n][j];
        float uu = accU[m][n][j];
        float pv = (g / (1.f + expf(-g))) * uu;
        int rl = wm * 64 + m * 16 + rbase + j;
        int cl = wn * 64 + n * 16 + lrow;
        P[(size_t)(row0 + rl) * I_DIM + n0 + cl] = f2bf(pv);
      }
    }
  }
}

// ---------------- Stage B: O = P @ down^T, weighted scatter DIRECTLY to out ----------------
// phase 0 (slot-0 buckets): out = 4*w*o ; phase 1 (slot-1): out += 4*w*o.
// Each phase touches every token at most once -> race-free, deterministic.
template <int PRE>
__global__ __launch_bounds__(256) void moe_stage_b(
    const unsigned short* __restrict__ Pb,
    const float* __restrict__ dwf, const unsigned short* __restrict__ dwb,
    const int* __restrict__ row2pair, const int* __restrict__ tileOff,
    const float* __restrict__ topw, float* __restrict__ out, int phase) {
  __shared__ int sPair[128];
  __shared__ __align__(16) unsigned short sA[128 * 64];
  __shared__ __align__(16) unsigned short sB[128 * 64];
  int mtEnd = phase ? tileOff[16] : tileOff[8];
  int mt = (phase ? tileOff[8] : 0) + blockIdx.x;
  if (mt >= mtEnd) return;
  int nt = blockIdx.y;
  int b = 0;
#pragma unroll
  for (int k = 1; k < 16; ++k) if (tileOff[k] <= mt) b = k;
  int e = b & 7;
  int row0 = mt * 128, h0 = nt * 128;
  int tid = threadIdx.x;
  if (tid < 128) sPair[tid] = row2pair[row0 + tid];
  __syncthreads();
  int lane = tid & 63, w = tid >> 6;
  int wm = w >> 1, wn = w & 1;
  int rloc = lane >> 3, cch = lane & 7, swz = cch ^ rloc;
  size_t wb = (size_t)e * ((size_t)H_DIM * I_DIM);

  const unsigned short* srcP[4]; const unsigned short* srcD[4]; const float* fD[4];
#pragma unroll
  for (int i = 0; i < 4; ++i) {
    int s = 4 * w + i;
    int row = s * 8 + rloc;
    srcP[i] = Pb + (size_t)(row0 + row) * I_DIM + swz * 8;   // P always bf16
    if constexpr (PRE) {
      srcD[i] = dwb + wb + (size_t)(h0 + row) * I_DIM + swz * 8;
    } else {
      fD[i] = dwf + wb + (size_t)(h0 + row) * I_DIM + cch * 8;
    }
  }
  int wrswz = rloc * 64 + (swz << 3);
  f32x4 acc[4][4] = {};
  int lrow = lane & 15, grp = lane >> 4, sw7 = lane & 7;

  for (int kk = 0; kk < I_DIM; kk += 64) {
#pragma unroll
    for (int i = 0; i < 4; ++i) {
      int lo = (4 * w + i) * 512;
      gll16(srcP[i] + kk, (void*)&sA[lo]);
      if constexpr (PRE) gll16(srcD[i] + kk, (void*)&sB[lo]);
    }
    if constexpr (!PRE) {
#pragma unroll
      for (int i = 0; i < 4; ++i) {
        int o = (4 * w + i) * 512 + wrswz;
        f32x4 x0 = *reinterpret_cast<const f32x4*>(fD[i] + kk);
        f32x4 x1 = *reinterpret_cast<const f32x4*>(fD[i] + kk + 4);
        u16x8 r = {f2bf(x0[0]), f2bf(x0[1]), f2bf(x0[2]), f2bf(x0[3]),
                   f2bf(x1[0]), f2bf(x1[1]), f2bf(x1[2]), f2bf(x1[3])};
        *reinterpret_cast<u16x8*>(&sB[o]) = r;
      }
    }
    asm volatile("s_waitcnt vmcnt(0)" ::: "memory");
    __syncthreads();
#pragma unroll
    for (int ks = 0; ks < 2; ++ks) {
      int cs = ((ks * 4 + grp) ^ sw7) << 3;
      bfv a[4], bb[4];
#pragma unroll
      for (int m = 0; m < 4; ++m)
        a[m] = *reinterpret_cast<const bfv*>(&sA[(wm * 64 + m * 16 + lrow) * 64 + cs]);
#pragma unroll
      for (int n = 0; n < 4; ++n)
        bb[n] = *reinterpret_cast<const bfv*>(&sB[(wn * 64 + n * 16 + lrow) * 64 + cs]);
#pragma unroll
      for (int m = 0; m < 4; ++m) {
#pragma unroll
        for (int n = 0; n < 4; ++n)
          acc[m][n] = __builtin_amdgcn_mfma_f32_16x16x32_bf16(a[m], bb[n], acc[m][n], 0, 0, 0);
      }
    }
    __syncthreads();
  }
  int rbase = grp << 2;
#pragma unroll
  for (int m = 0; m < 4; ++m) {
#pragma unroll
    for (int j = 0; j < 4; ++j) {
      int rl = wm * 64 + m * 16 + rbase + j;
      int pr = sPair[rl];
      if (pr < 0) continue;
      float wgt = topw[pr] * 4.f;   // SCALING = E/K = 4
      float* orow = out + (size_t)(pr >> 1) * H_DIM + h0 + wn * 64 + lrow;
      if (phase) {
#pragma unroll
        for (int n = 0; n < 4; ++n) orow[n * 16] += wgt * acc[m][n][j];
      } else {
#pragma unroll
        for (int n = 0; n < 4; ++n) orow[n * 16] = wgt * acc[m][n][j];
      }
    }
  }
}

// ---------------- launch ----------------
// ws layout (bytes):
//   P        @ 0           : 18432*1024*2 = 37,748,736
//   probs    @ 37,748,736  : 262,144
//   topw     @ 38,010,880  : 65,536
//   topi     @ 38,076,416  : 65,536
//   row2pair @ 38,141,952  : 73,728
//   ctrl     @ 38,215,680  : 512   (counts[16], cursors[16], impSum[8], tileOff[17])
//   W1       @ 38,216,192  : 33,554,432  (gate bf16; reused for down bf16 after stage A)
//   W2       @ 71,770,624  : 33,554,432  (up bf16)
//   Xb       @ 105,325,056 : 33,554,432  (X bf16)
//   REQ = 138,879,488 ; fallback to PRE=0 (reg-staged convert) if ws smaller.
extern "C" void kernel_launch(void* const* d_in, const int* in_sizes, int n_in,
                              void* d_out, int out_size, void* d_ws, size_t ws_size,
                              hipStream_t stream) {
  const float* X = (const float*)d_in[0];
  const float* norm_w = (const float*)d_in[1];
  const float* router_w = (const float*)d_in[2];
  const float* gate_w = (const float*)d_in[3];
  const float* up_w = (const float*)d_in[4];
  const float* down_w = (const float*)d_in[5];
  float* out = (float*)d_out;

  char* ws = (char*)d_ws;
  unsigned short* P = (unsigned short*)(ws);
  float* probs = (float*)(ws + 37748736);
  float* topw = (float*)(ws + 38010880);
  int* topi = (int*)(ws + 38076416);
  int* row2pair = (int*)(ws + 38141952);
  char* ctrl = ws + 38215680;
  unsigned int* counts = (unsigned int*)(ctrl);
  unsigned int* cursors = (unsigned int*)(ctrl + 64);
  float* impSum = (float*)(ctrl + 128);
  int* tileOff = (int*)(ctrl + 192);
  unsigned short* W1 = (unsigned short*)(ws + 38216192);   // gate, then down
  unsigned short* W2 = (unsigned short*)(ws + 71770624);   // up
  unsigned short* Xb = (unsigned short*)(ws + 105325056);
  const size_t REQ = 138879488;
  const bool pre = ws_size >= REQ;

  hipMemsetAsync(ctrl, 0, 512, stream);
  hipMemsetAsync(row2pair, 0xFF, (size_t)TOT_ROWS * 4, stream);

  const int N8 = (N_EXPERTS * I_DIM * H_DIM) / 8;   // 2,097,152
  if (pre) {
    moe_convert_kernel<<<N8 / 256, 256, 0, stream>>>(gate_w, W1, N8);
    moe_convert_kernel<<<N8 / 256, 256, 0, stream>>>(up_w, W2, N8);
  }
  moe_router_kernel<<<T_TOKENS, 256, 0, stream>>>(X, norm_w, router_w, probs, topw, topi,
                                                  counts, Xb, pre ? 1 : 0);
  moe_importance_kernel<<<N_EXPERTS, 256, 0, stream>>>(probs, impSum);
  moe_offsets_aux_kernel<<<1, 64, 0, stream>>>(counts, impSum, tileOff, out + 16777216);
  moe_assign_kernel<<<PAIRS / 256, 256, 0, stream>>>(topi, tileOff, cursors, row2pair);

  if (pre) {
    moe_stage_a<1><<<dim3(TOT_TILES, I_DIM / 128), 256, 0, stream>>>(
        X, Xb, gate_w, up_w, W1, W2, row2pair, tileOff, P);
    moe_convert_kernel<<<N8 / 256, 256, 0, stream>>>(down_w, W1, N8);  // gate dead now
    moe_stage_b<1><<<dim3(PHASE_TILES, H_DIM / 128), 256, 0, stream>>>(
        P, down_w, W1, row2pair, tileOff, topw, out, 0);
    moe_stage_b<1><<<dim3(PHASE_TILES, H_DIM / 128), 256, 0, stream>>>(
        P, down_w, W1, row2pair, tileOff, topw, out, 1);
  } else {
    moe_stage_a<0><<<dim3(TOT_TILES, I_DIM / 128), 256, 0, stream>>>(
        X, Xb, gate_w, up_w, W1, W2, row2pair, tileOff, P);
    moe_stage_b<0><<<dim3(PHASE_TILES, H_DIM / 128), 256, 0, stream>>>(
        P, down_w, W1, row2pair, tileOff, topw, out, 0);
    moe_stage_b<0><<<dim3(PHASE_TILES, H_DIM / 128), 256, 0, stream>>>(
        P, down_w, W1, row2pair, tileOff, topw, out, 1);
  }
}